// Round 18
// baseline (98.912 us; speedup 1.0000x reference)
//
#include <hip/hip_runtime.h>
#include <hip/hip_bf16.h>
#include <stdint.h>

#define F_DIM 512
#define H_DIM 256
#define B_DIM 128
#define M_BLK 128
#define NCHUNK 16   // 512 / 32
#define NBUF 2

typedef __bf16 bf16x8 __attribute__((ext_vector_type(8)));
typedef float  f32x4  __attribute__((ext_vector_type(4)));

// ---- one-time W1 f32 [K=512][C=256] -> bf16 transposed [C=256][K=512] ----
__global__ __launch_bounds__(256) void convert_w1_kernel(
    const float* __restrict__ W1, __bf16* __restrict__ W1t) {
    int t = blockIdx.x * 256 + threadIdx.x;   // t = c*512 + k
    int c = t >> 9;
    int k = t & 511;
    W1t[t] = (__bf16)W1[k * H_DIM + c];
}

__device__ inline void gload_lds16(const float* g, float* lds) {
    __builtin_amdgcn_global_load_lds(
        (const __attribute__((address_space(1))) uint32_t*)g,
        (__attribute__((address_space(3))) uint32_t*)lds, 16, 0, 0);
}
__device__ inline void gload_lds16b(const __bf16* g, __bf16* lds) {
    __builtin_amdgcn_global_load_lds(
        (const __attribute__((address_space(1))) uint32_t*)g,
        (__attribute__((address_space(3))) uint32_t*)lds, 16, 0, 0);
}

// B seg swizzle: 2-way-max bank pattern for the [col][64B] layout
__device__ inline int bswz(int col) { return (col & 3) ^ ((col >> 2) & 3); }

// ---- main fused kernel: R17 schedule with 2x-bigger per-WAVE tile ----
// Theory: kernel is LDS-read-pipe bound (ds_read_b128 ~12cy x 192/CU-chunk
// ~= the measured 2830cy cadence). Per-wave tile 32x64 -> 64x128 halves LDS
// bytes per FLOP (A 2R + B C bytes per 32k: 128B/2048FLOP -> 256B/8192FLOP).
// 256 thr = 4 waves (2m x 2n), block tile 128x256, acc[4][8] (~128 VGPR,
// natural allocation, NO min-waves clause - 3 spill incidents). LDS 66 KB
// -> 2 blocks/CU. Same counted-vmcnt discipline: 8 VMEM/thread/chunk.
template<bool USE_PARTIAL>
__global__ __launch_bounds__(256) void fused_mlp_kernel(
    const float* __restrict__ pos,
    const float* __restrict__ mass_center,
    const float* __restrict__ scaler,
    const int*   __restrict__ batch_index,
    const __bf16* __restrict__ W1t,
    const float* __restrict__ b1,
    const float* __restrict__ W2,
    const float* __restrict__ b2,
    float* __restrict__ outp,
    int N)
{
    __shared__ float  A_lds[NBUF][M_BLK][32];    // 2 x 16 KB
    __shared__ __bf16 Bc_lds[NBUF][H_DIM][32];   // 2 x 16 KB
    __shared__ float  q_lds[M_BLK];
    __shared__ float  pb[B_DIM];

    const int tid    = threadIdx.x;      // 0..255
    const int lane   = tid & 63;
    const int wid    = tid >> 6;         // 0..3
    const int wave_m = wid >> 1;         // 0..1 -> 64-row strip
    const int wave_n = wid & 1;          // 0..1 -> 128-col strip
    const int lrow   = lane & 15;
    const int kq     = (lane >> 4) * 8;  // k-elem offset of this lane's fragment
    const int row_base = blockIdx.x * M_BLK;

    if (tid < M_BLK) q_lds[tid] = 0.f;
    if (USE_PARTIAL && tid < B_DIM) pb[tid] = 0.f;

    // -- A staging (4 passes x 256 threads = 1024 16B slots):
    //    slot s=p*256+tid -> row s>>3, phys seg s&7; SOURCE seg ^ (row&7).
    const float* gsA[4];
    // -- B staging (4 passes): slot s -> col s>>2, phys seg s&3;
    //    SOURCE seg ^ bswz(col).
    const __bf16* gsB[4];
    #pragma unroll
    for (int p = 0; p < 4; ++p) {
        int sA   = p * 256 + tid;
        int rowA = sA >> 3;
        int segA = (sA & 7) ^ (rowA & 7);
        int grA  = row_base + rowA; if (grA >= N) grA = N - 1;
        gsA[p] = scaler + (size_t)grA * F_DIM + segA * 4;
        int sB   = p * 256 + tid;
        int colB = sB >> 2;
        int segB = (sB & 3) ^ bswz(colB);
        gsB[p] = W1t + (size_t)colB * F_DIM + segB * 8;
    }

#define STAGE(buf, c) do {                                                    \
        _Pragma("unroll")                                                     \
        for (int p = 0; p < 4; ++p) {                                         \
            gload_lds16 (gsA[p] + (c) * 32,                                   \
                         &A_lds[(buf)][0][0] + p * 1024 + wid * 256);         \
            gload_lds16b(gsB[p] + (c) * 32,                                   \
                         &Bc_lds[(buf)][0][0] + p * 2048 + wid * 512);        \
        }                                                                     \
    } while (0)

    f32x4 acc[4][8];
    #pragma unroll
    for (int mi = 0; mi < 4; ++mi)
        #pragma unroll
        for (int ni = 0; ni < 8; ++ni)
            acc[mi][ni] = (f32x4){0.f, 0.f, 0.f, 0.f};

    // prologue: 2 chunks in flight (16 VMEM/thread)
    STAGE(0, 0);
    STAGE(1, 1);

    #pragma unroll
    for (int kc = 0; kc < NCHUNK; ++kc) {
        // counted wait: stage(kc) landed; stage(kc+1)'s 8 stay in flight
        if (kc < NCHUNK - 1) asm volatile("s_waitcnt vmcnt(8)" ::: "memory");
        else                 asm volatile("s_waitcnt vmcnt(0)" ::: "memory");
        __builtin_amdgcn_s_barrier();

        // ---- compute chunk kc from buf kc&1 (all operands from LDS) ----
        const int buf = kc & 1;
        bf16x8 af[4];
        #pragma unroll
        for (int mi = 0; mi < 4; ++mi) {
            const int rA = wave_m * 64 + mi * 16 + lrow;
            const int sw = (rA & 7) << 4;
            const char* rb = (const char*)&A_lds[buf][0][0] + rA * 128;
            f32x4 a0 = *(const f32x4*)(rb + ((kq * 4) ^ sw));
            f32x4 a1 = *(const f32x4*)(rb + ((kq * 4 + 16) ^ sw));
            #pragma unroll
            for (int j = 0; j < 4; ++j) {
                af[mi][j]     = (__bf16)a0[j];
                af[mi][4 + j] = (__bf16)a1[j];
            }
        }
        bf16x8 bfrag[8];
        #pragma unroll
        for (int ni = 0; ni < 8; ++ni) {
            const int col = wave_n * 128 + ni * 16 + lrow;
            const int ps  = (lane >> 4) ^ bswz(col);   // physical 16B seg
            bfrag[ni] = *(const bf16x8*)((const char*)&Bc_lds[buf][0][0]
                                         + col * 64 + ps * 16);
        }
        __builtin_amdgcn_s_setprio(1);
        #pragma unroll
        for (int mi = 0; mi < 4; ++mi)
            #pragma unroll
            for (int ni = 0; ni < 8; ++ni)
                acc[mi][ni] = __builtin_amdgcn_mfma_f32_16x16x32_bf16(
                    af[mi], bfrag[ni], acc[mi][ni], 0, 0, 0);
        __builtin_amdgcn_s_setprio(0);

        __builtin_amdgcn_s_barrier();   // all readers done with buf kc&1
        if (kc + 2 < NCHUNK)
            STAGE(buf, kc + 2);         // refill the buffer just vacated
    }
#undef STAGE

    // ---- epilogue: silu + dot(W2), reduce over the 16 col-lanes ----
    float qp[4][4];
    #pragma unroll
    for (int mi = 0; mi < 4; ++mi)
        #pragma unroll
        for (int r = 0; r < 4; ++r) qp[mi][r] = 0.f;

    #pragma unroll
    for (int ni = 0; ni < 8; ++ni) {
        int c = wave_n * 128 + ni * 16 + lrow;
        float b1c = b1[c];
        float w2c = W2[c];
        #pragma unroll
        for (int mi = 0; mi < 4; ++mi)
            #pragma unroll
            for (int r = 0; r < 4; ++r) {
                float h = acc[mi][ni][r] + b1c;
                float s = h / (1.0f + __expf(-h));
                qp[mi][r] += s * w2c;
            }
    }
    #pragma unroll
    for (int off = 1; off < 16; off <<= 1)
        #pragma unroll
        for (int mi = 0; mi < 4; ++mi)
            #pragma unroll
            for (int r = 0; r < 4; ++r)
                qp[mi][r] += __shfl_xor(qp[mi][r], off, 64);

    if ((lane & 15) == 0) {
        int rgrp = lane >> 4;
        #pragma unroll
        for (int mi = 0; mi < 4; ++mi)
            #pragma unroll
            for (int r = 0; r < 4; ++r)
                atomicAdd(&q_lds[wave_m * 64 + mi * 16 + rgrp * 4 + r], qp[mi][r]);
    }
    __syncthreads();

    if (tid < M_BLK) {
        int grow = row_base + tid;
        if (grow < N) {
            float q  = q_lds[tid] + b2[0];
            int   bi = batch_index[grow];
            float dx = pos[grow * 3 + 0] - mass_center[bi * 3 + 0];
            float dy = pos[grow * 3 + 1] - mass_center[bi * 3 + 1];
            float dz = pos[grow * 3 + 2] - mass_center[bi * 3 + 2];
            float val = q * (dx * dx + dy * dy + dz * dz);
            if (USE_PARTIAL) atomicAdd(&pb[bi], val);
            else             atomicAdd(&outp[bi], val);
        }
    }
    if (USE_PARTIAL) {
        __syncthreads();
        if (tid < B_DIM)
            outp[(size_t)blockIdx.x * B_DIM + tid] = pb[tid];
    }
}

// ---- reduce per-block partials [nblk][128] -> out[128] ----
__global__ __launch_bounds__(256) void reduce_partials_kernel(
    const float* __restrict__ partial, float* __restrict__ out, int nblk) {
    int b = blockIdx.x;
    float s = 0.f;
    for (int i = threadIdx.x; i < nblk; i += 256)
        s += partial[(size_t)i * B_DIM + b];
    #pragma unroll
    for (int off = 1; off < 64; off <<= 1)
        s += __shfl_xor(s, off, 64);
    __shared__ float wsum[4];
    if ((threadIdx.x & 63) == 0) wsum[threadIdx.x >> 6] = s;
    __syncthreads();
    if (threadIdx.x == 0)
        out[b] = wsum[0] + wsum[1] + wsum[2] + wsum[3];
}

extern "C" void kernel_launch(void* const* d_in, const int* in_sizes, int n_in,
                              void* d_out, int out_size, void* d_ws, size_t ws_size,
                              hipStream_t stream) {
    const float* pos         = (const float*)d_in[0];
    const float* mass_center = (const float*)d_in[1];
    const float* scaler      = (const float*)d_in[2];
    // d_in[3] = vector : unused by the reference computation
    const int*   batch_index = (const int*)d_in[4];
    const float* W1          = (const float*)d_in[5];
    const float* b1          = (const float*)d_in[6];
    const float* W2          = (const float*)d_in[7];
    const float* b2          = (const float*)d_in[8];
    float* out = (float*)d_out;
    (void)n_in; (void)out_size;

    int N = in_sizes[0] / 3;
    int nblk = (N + M_BLK - 1) / M_BLK;

    size_t w1t_bytes  = (size_t)F_DIM * H_DIM * sizeof(__bf16);   // 256 KB
    size_t part_bytes = (size_t)nblk * B_DIM * sizeof(float);

    __bf16* W1t = (__bf16*)d_ws;
    convert_w1_kernel<<<(F_DIM * H_DIM) / 256, 256, 0, stream>>>(W1, W1t);

    if (ws_size >= w1t_bytes + part_bytes) {
        float* partial = (float*)((char*)d_ws + w1t_bytes);
        fused_mlp_kernel<true><<<nblk, 256, 0, stream>>>(
            pos, mass_center, scaler, batch_index, W1t, b1, W2, b2, partial, N);
        reduce_partials_kernel<<<B_DIM, 256, 0, stream>>>(partial, out, nblk);
    } else {
        hipMemsetAsync(out, 0, B_DIM * sizeof(float), stream);
        fused_mlp_kernel<false><<<nblk, 256, 0, stream>>>(
            pos, mass_center, scaler, batch_index, W1t, b1, W2, b2, out, N);
    }
}

// Round 19
// 77.472 us; speedup vs baseline: 1.2767x; 1.2767x over previous
//
#include <hip/hip_runtime.h>
#include <hip/hip_bf16.h>
#include <stdint.h>

#define F_DIM 512
#define H_DIM 256
#define B_DIM 128
#define M_BLK 64
#define NCHUNK 16   // 512 / 32
#define NBUF 2

typedef __bf16 bf16x8 __attribute__((ext_vector_type(8)));
typedef float  f32x4  __attribute__((ext_vector_type(4)));

// ---- one-time W1 f32 [K=512][C=256] -> bf16 transposed [C=256][K=512] ----
__global__ __launch_bounds__(256) void convert_w1_kernel(
    const float* __restrict__ W1, __bf16* __restrict__ W1t) {
    int t = blockIdx.x * 256 + threadIdx.x;   // t = c*512 + k
    int c = t >> 9;
    int k = t & 511;
    W1t[t] = (__bf16)W1[k * H_DIM + c];
}

__device__ inline void gload_lds16(const float* g, float* lds) {
    __builtin_amdgcn_global_load_lds(
        (const __attribute__((address_space(1))) uint32_t*)g,
        (__attribute__((address_space(3))) uint32_t*)lds, 16, 0, 0);
}
__device__ inline void gload_lds16b(const __bf16* g, __bf16* lds) {
    __builtin_amdgcn_global_load_lds(
        (const __attribute__((address_space(1))) uint32_t*)g,
        (__attribute__((address_space(3))) uint32_t*)lds, 16, 0, 0);
}

// B seg swizzle: 2-way-max bank pattern for the [col][64B] layout
__device__ inline int bswz(int col) { return (col & 3) ^ ((col >> 2) & 3); }

// ---- FINAL kernel: R17 (best measured: 77.5 us total; reproduced 3x) ----
// NBUF=2, 48.75 KB LDS -> 3 blocks/CU (24 waves/CU). Per chunk: counted
// vmcnt(3) [own stage(kc) landed; stage(kc+1) in flight] -> barrier ->
// ds_read + 16 MFMA (setprio-wrapped) -> barrier -> STAGE(kc+2) into the
// vacated buffer. Issue early, wait late; never drain in the main loop.
// Epilogue: per-block partials + reduce kernel (NO hot-path global atomics:
// 100K RMWs on 128 words serialize at the TCC, +100us measured R11/R12).
// Structural alternatives measured worse: NBUF=3 single-barrier (R11),
// M=128 (R14), half-chunk 4-blk/CU (R16), 64x128/wave tile (R18), register
// pipelines (R5), persistent blocks (R7), min-waves bounds (R9/R15 spills).
template<bool USE_PARTIAL>
__global__ __launch_bounds__(512, 6) void fused_mlp_kernel(
    const float* __restrict__ pos,
    const float* __restrict__ mass_center,
    const float* __restrict__ scaler,
    const int*   __restrict__ batch_index,
    const __bf16* __restrict__ W1t,
    const float* __restrict__ b1,
    const float* __restrict__ W2,
    const float* __restrict__ b2,
    float* __restrict__ outp,
    int N)
{
    __shared__ float  A_lds[NBUF][M_BLK][32];    // 2 x 8 KB
    __shared__ __bf16 Bc_lds[NBUF][H_DIM][32];   // 2 x 16 KB
    __shared__ float  q_lds[M_BLK];
    __shared__ float  pb[B_DIM];

    const int tid    = threadIdx.x;
    const int lane   = tid & 63;
    const int wid    = tid >> 6;     // 0..7
    const int wave_m = wid >> 2;     // 0..1 -> 32-row strip
    const int wave_n = wid & 3;      // 0..3 -> 64-col strip
    const int lrow   = lane & 15;
    const int kq     = (lane >> 4) * 8;   // k-elem offset of this lane's fragment
    const int row_base = blockIdx.x * M_BLK;

    if (tid < M_BLK) q_lds[tid] = 0.f;
    if (USE_PARTIAL && tid < B_DIM) pb[tid] = 0.f;

    // -- A staging: slot t -> row t>>3, phys 16B seg t&7; source seg ^ (row&7)
    //    (linear LDS dest + pre-swizzled source; read side XOR-unswizzles).
    const int srow = tid >> 3;
    const int sseg = (tid & 7) ^ (srow & 7);
    int grA = row_base + srow; if (grA >= N) grA = N - 1;
    const float* gsA = scaler + (size_t)grA * F_DIM + sseg * 4;

    // -- B staging: pass p slot s=p*512+tid -> col s>>2, phys seg s&3;
    //    source seg = (s&3) ^ bswz(col).
    const int c0 = tid >> 2,         g0 = (tid & 3) ^ bswz(c0);
    const int c1 = (512 + tid) >> 2, g1 = ((512 + tid) & 3) ^ bswz(c1);
    const __bf16* gsB0 = W1t + (size_t)c0 * F_DIM + g0 * 8;
    const __bf16* gsB1 = W1t + (size_t)c1 * F_DIM + g1 * 8;

#define STAGE(buf, c) do {                                                      \
        gload_lds16 (gsA  + (c) * 32, &A_lds[(buf)][0][0] + wid * 256);         \
        gload_lds16b(gsB0 + (c) * 32, &Bc_lds[(buf)][0][0] + wid * 512);        \
        gload_lds16b(gsB1 + (c) * 32, &Bc_lds[(buf)][0][0] + 4096 + wid * 512); \
    } while (0)

    f32x4 acc[2][4];
    #pragma unroll
    for (int mi = 0; mi < 2; ++mi)
        #pragma unroll
        for (int ni = 0; ni < 4; ++ni)
            acc[mi][ni] = (f32x4){0.f, 0.f, 0.f, 0.f};

    // prologue: 2 chunks in flight (6 VMEM/thread)
    STAGE(0, 0);
    STAGE(1, 1);

    #pragma unroll
    for (int kc = 0; kc < NCHUNK; ++kc) {
        // counted wait: stage(kc) landed; stage(kc+1) stays in flight
        if (kc < NCHUNK - 1) asm volatile("s_waitcnt vmcnt(3)" ::: "memory");
        else                 asm volatile("s_waitcnt vmcnt(0)" ::: "memory");
        __builtin_amdgcn_s_barrier();

        // ---- compute chunk kc from buf kc&1 (all operands from LDS) ----
        const int buf = kc & 1;
        bf16x8 af[2];
        #pragma unroll
        for (int mi = 0; mi < 2; ++mi) {
            const int rA = wave_m * 32 + mi * 16 + lrow;
            const int sw = (rA & 7) << 4;
            const char* rb = (const char*)&A_lds[buf][0][0] + rA * 128;
            f32x4 a0 = *(const f32x4*)(rb + ((kq * 4) ^ sw));
            f32x4 a1 = *(const f32x4*)(rb + ((kq * 4 + 16) ^ sw));
            #pragma unroll
            for (int j = 0; j < 4; ++j) {
                af[mi][j]     = (__bf16)a0[j];
                af[mi][4 + j] = (__bf16)a1[j];
            }
        }
        bf16x8 bfrag[4];
        #pragma unroll
        for (int ni = 0; ni < 4; ++ni) {
            const int col = wave_n * 64 + ni * 16 + lrow;
            const int ps  = (lane >> 4) ^ bswz(col);   // physical 16B seg
            bfrag[ni] = *(const bf16x8*)((const char*)&Bc_lds[buf][0][0]
                                         + col * 64 + ps * 16);
        }
        __builtin_amdgcn_s_setprio(1);   // T5: favor MFMA-entering wave
        #pragma unroll
        for (int mi = 0; mi < 2; ++mi)
            #pragma unroll
            for (int ni = 0; ni < 4; ++ni)
                acc[mi][ni] = __builtin_amdgcn_mfma_f32_16x16x32_bf16(
                    af[mi], bfrag[ni], acc[mi][ni], 0, 0, 0);
        __builtin_amdgcn_s_setprio(0);

        __builtin_amdgcn_s_barrier();   // all readers done with buf kc&1
        if (kc + 2 < NCHUNK)
            STAGE(buf, kc + 2);         // refill the buffer just vacated
    }
#undef STAGE

    // ---- epilogue: silu + dot(W2), reduce over the 16 col-lanes ----
    float qp[2][4];
    #pragma unroll
    for (int mi = 0; mi < 2; ++mi)
        #pragma unroll
        for (int r = 0; r < 4; ++r) qp[mi][r] = 0.f;

    #pragma unroll
    for (int ni = 0; ni < 4; ++ni) {
        int c = wave_n * 64 + ni * 16 + lrow;
        float b1c = b1[c];
        float w2c = W2[c];
        #pragma unroll
        for (int mi = 0; mi < 2; ++mi)
            #pragma unroll
            for (int r = 0; r < 4; ++r) {
                float h = acc[mi][ni][r] + b1c;
                float s = h / (1.0f + __expf(-h));
                qp[mi][r] += s * w2c;
            }
    }
    #pragma unroll
    for (int off = 1; off < 16; off <<= 1)
        #pragma unroll
        for (int mi = 0; mi < 2; ++mi)
            #pragma unroll
            for (int r = 0; r < 4; ++r)
                qp[mi][r] += __shfl_xor(qp[mi][r], off, 64);

    if ((lane & 15) == 0) {
        int rgrp = lane >> 4;
        #pragma unroll
        for (int mi = 0; mi < 2; ++mi)
            #pragma unroll
            for (int r = 0; r < 4; ++r)
                atomicAdd(&q_lds[wave_m * 32 + mi * 16 + rgrp * 4 + r], qp[mi][r]);
    }
    __syncthreads();

    if (tid < M_BLK) {
        int grow = row_base + tid;
        if (grow < N) {
            float q  = q_lds[tid] + b2[0];
            int   bi = batch_index[grow];
            float dx = pos[grow * 3 + 0] - mass_center[bi * 3 + 0];
            float dy = pos[grow * 3 + 1] - mass_center[bi * 3 + 1];
            float dz = pos[grow * 3 + 2] - mass_center[bi * 3 + 2];
            float val = q * (dx * dx + dy * dy + dz * dz);
            if (USE_PARTIAL) atomicAdd(&pb[bi], val);
            else             atomicAdd(&outp[bi], val);
        }
    }
    if (USE_PARTIAL) {
        __syncthreads();
        if (tid < B_DIM)
            outp[(size_t)blockIdx.x * B_DIM + tid] = pb[tid];
    }
}

// ---- reduce per-block partials [nblk][128] -> out[128] ----
__global__ __launch_bounds__(256) void reduce_partials_kernel(
    const float* __restrict__ partial, float* __restrict__ out, int nblk) {
    int b = blockIdx.x;
    float s = 0.f;
    for (int i = threadIdx.x; i < nblk; i += 256)
        s += partial[(size_t)i * B_DIM + b];
    #pragma unroll
    for (int off = 1; off < 64; off <<= 1)
        s += __shfl_xor(s, off, 64);
    __shared__ float wsum[4];
    if ((threadIdx.x & 63) == 0) wsum[threadIdx.x >> 6] = s;
    __syncthreads();
    if (threadIdx.x == 0)
        out[b] = wsum[0] + wsum[1] + wsum[2] + wsum[3];
}

extern "C" void kernel_launch(void* const* d_in, const int* in_sizes, int n_in,
                              void* d_out, int out_size, void* d_ws, size_t ws_size,
                              hipStream_t stream) {
    const float* pos         = (const float*)d_in[0];
    const float* mass_center = (const float*)d_in[1];
    const float* scaler      = (const float*)d_in[2];
    // d_in[3] = vector : unused by the reference computation
    const int*   batch_index = (const int*)d_in[4];
    const float* W1          = (const float*)d_in[5];
    const float* b1          = (const float*)d_in[6];
    const float* W2          = (const float*)d_in[7];
    const float* b2          = (const float*)d_in[8];
    float* out = (float*)d_out;
    (void)n_in; (void)out_size;

    int N = in_sizes[0] / 3;
    int nblk = (N + M_BLK - 1) / M_BLK;

    size_t w1t_bytes  = (size_t)F_DIM * H_DIM * sizeof(__bf16);   // 256 KB
    size_t part_bytes = (size_t)nblk * B_DIM * sizeof(float);

    __bf16* W1t = (__bf16*)d_ws;
    convert_w1_kernel<<<(F_DIM * H_DIM) / 256, 256, 0, stream>>>(W1, W1t);

    if (ws_size >= w1t_bytes + part_bytes) {
        float* partial = (float*)((char*)d_ws + w1t_bytes);
        fused_mlp_kernel<true><<<nblk, 512, 0, stream>>>(
            pos, mass_center, scaler, batch_index, W1t, b1, W2, b2, partial, N);
        reduce_partials_kernel<<<B_DIM, 256, 0, stream>>>(partial, out, nblk);
    } else {
        hipMemsetAsync(out, 0, B_DIM * sizeof(float), stream);
        fused_mlp_kernel<false><<<nblk, 512, 0, stream>>>(
            pos, mass_center, scaler, batch_index, W1t, b1, W2, b2, out, N);
    }
}